// Round 2
// baseline (938.037 us; speedup 1.0000x reference)
//
#include <hip/hip_runtime.h>
#include <math.h>

// ---------------- problem constants ----------------
#define DD 128
#define SPLIT 50000
#define NN1 50000
#define NN2 30000
#define NN3 10000
#define EE0 500000
#define EE1 300000
#define EE2 100000
#define NEG 0.2f

// ordered-uint encoding for float atomicMax
static __device__ __forceinline__ unsigned f2o(float f) {
  unsigned u = __float_as_uint(f);
  return (u & 0x80000000u) ? ~u : (u | 0x80000000u);
}
static __device__ __forceinline__ float o2f(unsigned e) {
  return (e & 0x80000000u) ? __uint_as_float(e & 0x7FFFFFFFu) : __uint_as_float(~e);
}

// ---------------- layer 0: scatter-sum x rows + degree ----------------
__global__ __launch_bounds__(256) void scatter0_kernel(
    const float* __restrict__ x, const int* __restrict__ src,
    const int* __restrict__ dst, float* __restrict__ acc, float* __restrict__ deg)
{
  int e = blockIdx.x * 4 + (threadIdx.x >> 6);
  if (e >= EE0) return;
  int lane = threadIdx.x & 63;
  int s = src[e], d = dst[e];
  if (lane == 0) atomicAdd(&deg[d], 1.0f);
  if (s >= SPLIT) {
    const float* xp = x + (size_t)(s - SPLIT) * DD;
    float* ap = acc + (size_t)d * DD;
    atomicAdd(&ap[lane], xp[lane]);
    atomicAdd(&ap[lane + 64], xp[lane + 64]);
  }
}

// ---- C[N,128] = A[N,128] @ W[128,128]; deg!=null => *0.5/(deg+1e-16) ----
// 64 rows per block; W staged in two 64-row k-halves (total LDS 64 KB).
__global__ __launch_bounds__(256) void gemm128_kernel(
    const float* __restrict__ A, const float* __restrict__ W,
    float* __restrict__ C, int N, const float* __restrict__ deg)
{
  __shared__ float Al[64 * 128];
  __shared__ float Wl[64 * 128];
  int t = threadIdx.x;
  int cg = t & 31;   // 4-col group (cols 4*cg..4*cg+3)
  int rg = t >> 5;   // row group (8 rows each)
  int r0 = blockIdx.x << 6;
  int nrows = N - r0; if (nrows > 64) nrows = 64;

  const float4* Ag = (const float4*)(A + (size_t)r0 * DD);
  float4* Al4 = (float4*)Al;
  for (int i = t; i < nrows * 32; i += 256) Al4[i] = Ag[i];

  float acc[8][4] = {};
  const float4* W4 = (const float4*)W;
  float4* Wl4 = (float4*)Wl;
  const float4* Al4c = (const float4*)Al;

  for (int half = 0; half < 2; ++half) {
    __syncthreads();   // half0: nothing staged yet; half1: drain compute on Wl
    for (int i = t; i < 2048; i += 256) Wl4[i] = W4[half * 2048 + i];
    __syncthreads();   // Al (half0) + Wl ready
    const float4* Wl4c = (const float4*)Wl;
    int kb4 = half * 16;   // float4 k-offset into A rows
    for (int k4 = 0; k4 < 16; ++k4) {
      float4 w0 = Wl4c[(k4 * 4 + 0) * 32 + cg];
      float4 w1 = Wl4c[(k4 * 4 + 1) * 32 + cg];
      float4 w2 = Wl4c[(k4 * 4 + 2) * 32 + cg];
      float4 w3 = Wl4c[(k4 * 4 + 3) * 32 + cg];
#pragma unroll
      for (int r = 0; r < 8; ++r) {
        float4 a = Al4c[(rg * 8 + r) * 32 + kb4 + k4];
        acc[r][0] = fmaf(a.x, w0.x, acc[r][0]);
        acc[r][1] = fmaf(a.x, w0.y, acc[r][1]);
        acc[r][2] = fmaf(a.x, w0.z, acc[r][2]);
        acc[r][3] = fmaf(a.x, w0.w, acc[r][3]);
        acc[r][0] = fmaf(a.y, w1.x, acc[r][0]);
        acc[r][1] = fmaf(a.y, w1.y, acc[r][1]);
        acc[r][2] = fmaf(a.y, w1.z, acc[r][2]);
        acc[r][3] = fmaf(a.y, w1.w, acc[r][3]);
        acc[r][0] = fmaf(a.z, w2.x, acc[r][0]);
        acc[r][1] = fmaf(a.z, w2.y, acc[r][1]);
        acc[r][2] = fmaf(a.z, w2.z, acc[r][2]);
        acc[r][3] = fmaf(a.z, w2.w, acc[r][3]);
        acc[r][0] = fmaf(a.w, w3.x, acc[r][0]);
        acc[r][1] = fmaf(a.w, w3.y, acc[r][1]);
        acc[r][2] = fmaf(a.w, w3.z, acc[r][2]);
        acc[r][3] = fmaf(a.w, w3.w, acc[r][3]);
      }
    }
  }

#pragma unroll
  for (int r = 0; r < 8; ++r) {
    int rr = rg * 8 + r;
    if (rr < nrows) {
      float sc = 1.0f;
      if (deg) sc = 0.5f / (deg[r0 + rr] + 1e-16f);
      float4 o;
      o.x = acc[r][0] * sc; o.y = acc[r][1] * sc;
      o.z = acc[r][2] * sc; o.w = acc[r][3] * sc;
      ((float4*)(C + (size_t)(r0 + rr) * DD))[cg] = o;
    }
  }
}

// ---------------- BatchNorm: column stats then apply ----------------
__global__ __launch_bounds__(256) void bn_stats_kernel(
    const float* __restrict__ H, float* __restrict__ sums /*[256]*/)
{
  int t = threadIdx.x;
  int col = t & 127;
  float s = 0.f, q = 0.f;
  for (int r = blockIdx.x * 2 + (t >> 7); r < NN1; r += gridDim.x * 2) {
    float v = H[(size_t)r * DD + col];
    s += v; q += v * v;
  }
  __shared__ float ls[256], lq[256];
  ls[t] = s; lq[t] = q;
  __syncthreads();
  if (t < 128) {
    atomicAdd(&sums[col], ls[t] + ls[t + 128]);
    atomicAdd(&sums[128 + col], lq[t] + lq[t + 128]);
  }
}

__global__ __launch_bounds__(256) void bn_apply_kernel(
    float* __restrict__ H, const float* __restrict__ sums,
    const float* __restrict__ g, const float* __restrict__ b)
{
  const float invN = 1.0f / (float)NN1;
  size_t total = (size_t)NN1 * DD;
  for (size_t i = (size_t)blockIdx.x * 256 + threadIdx.x; i < total;
       i += (size_t)gridDim.x * 256) {
    int col = (int)(i & 127);
    float mu = sums[col] * invN;
    float var = sums[128 + col] * invN - mu * mu;
    float rs = rsqrtf(var + 1e-5f);
    H[i] = (H[i] - mu) * rs * g[col] + b[col];
  }
}

// ---------------- pass A: per-edge logits + segment max ----------------
__global__ __launch_bounds__(256) void edge_logits_kernel(
    const float* __restrict__ Q, const float* __restrict__ K,
    const float* __restrict__ EKT, const int* __restrict__ src,
    const int* __restrict__ dst, const int* __restrict__ et,
    float* __restrict__ LG, unsigned* __restrict__ M, int E)
{
  int e = blockIdx.x * 4 + (threadIdx.x >> 6);
  if (e >= E) return;
  int lane = threadIdx.x & 63;
  int s = src[e], d = dst[e];
  const float* kp = K + (size_t)s * DD;
  const float* qp = Q + (size_t)d * DD;
  float k0 = kp[lane], k1 = kp[lane + 64];
  if (EKT) {
    const float* ep = EKT + (size_t)et[e] * DD;
    k0 += ep[lane]; k1 += ep[lane + 64];
  }
  float p0 = qp[lane] * k0;
  float p1 = qp[lane + 64] * k1;
#pragma unroll
  for (int off = 8; off >= 1; off >>= 1) {
    p0 += __shfl_xor(p0, off);
    p1 += __shfl_xor(p1, off);
  }
  if ((lane & 15) == 0) {
    int h = lane >> 4;
    float l0 = p0 * 0.25f; l0 = (l0 >= 0.f) ? l0 : NEG * l0;
    float l1 = p1 * 0.25f; l1 = (l1 >= 0.f) ? l1 : NEG * l1;
    LG[(size_t)e * 8 + h] = l0;
    LG[(size_t)e * 8 + 4 + h] = l1;
    atomicMax(&M[(size_t)d * 8 + h], f2o(l0));
    atomicMax(&M[(size_t)d * 8 + 4 + h], f2o(l1));
  }
}

// ---------------- pass B: a = exp(l - m); segment sum ----------------
__global__ __launch_bounds__(256) void edge_exp_kernel(
    float* __restrict__ LG, const unsigned* __restrict__ M,
    float* __restrict__ SS, const int* __restrict__ dst, int E)
{
  int total = E * 8;
  for (int i = blockIdx.x * 256 + threadIdx.x; i < total; i += gridDim.x * 256) {
    int e = i >> 3, h = i & 7;
    int d = dst[e];
    float m = o2f(M[(size_t)d * 8 + h]);
    float a = expf(LG[i] - m);
    LG[i] = a;
    atomicAdd(&SS[(size_t)d * 8 + h], a);
  }
}

// ---------------- pass C: out[dst] += alpha * v (on top of Ws prefill) ----------------
__global__ __launch_bounds__(256) void edge_accum_kernel(
    const float* __restrict__ V, const float* __restrict__ EVT,
    const int* __restrict__ src, const int* __restrict__ dst,
    const int* __restrict__ et, const float* __restrict__ LG,
    const float* __restrict__ SS, float* __restrict__ OUT, int E)
{
  int e = blockIdx.x * 4 + (threadIdx.x >> 6);
  if (e >= E) return;
  int lane = threadIdx.x & 63;
  int s = src[e], d = dst[e];
  const float* vp = V + (size_t)s * DD;
  float v0 = vp[lane], v1 = vp[lane + 64];
  if (EVT) {
    const float* ep = EVT + (size_t)et[e] * DD;
    v0 += ep[lane]; v1 += ep[lane + 64];
  }
  int h0 = lane >> 4, h1 = 4 + (lane >> 4);
  float a0 = LG[(size_t)e * 8 + h0];
  float a1 = LG[(size_t)e * 8 + h1];
  float al0 = a0 / (SS[(size_t)d * 8 + h0] + 1e-16f);
  float al1 = a1 / (SS[(size_t)d * 8 + h1] + 1e-16f);
  float* op = OUT + (size_t)d * DD;
  atomicAdd(&op[lane], al0 * v0);
  atomicAdd(&op[lane + 64], al1 * v1);
}

// ---------------- in-place *0.5 (gated residual, BETA=0.5) ----------------
__global__ __launch_bounds__(256) void halve_kernel(float* __restrict__ O, int n)
{
  for (int i = blockIdx.x * 256 + threadIdx.x; i < n; i += gridDim.x * 256)
    O[i] *= 0.5f;
}

__global__ __launch_bounds__(256) void scale_out_kernel(
    const float* __restrict__ O, float* __restrict__ out, int n)
{
  for (int i = blockIdx.x * 256 + threadIdx.x; i < n; i += gridDim.x * 256)
    out[i] = 0.5f * O[i];
}

extern "C" void kernel_launch(void* const* d_in, const int* in_sizes, int n_in,
                              void* d_out, int out_size, void* d_ws, size_t ws_size,
                              hipStream_t stream)
{
  const float* x   = (const float*)d_in[0];
  const float* tt  = (const float*)d_in[1];
  const float* at  = (const float*)d_in[2];
  const float* Wv0 = (const float*)d_in[5];
  const float* Wq1 = (const float*)d_in[7];
  const float* Wk1 = (const float*)d_in[8];
  const float* Wv1 = (const float*)d_in[9];
  const float* Ws1 = (const float*)d_in[10];
  const float* Wek1= (const float*)d_in[11];
  const float* Wev1= (const float*)d_in[12];
  const float* Wq2 = (const float*)d_in[13];
  const float* Wk2 = (const float*)d_in[14];
  const float* Wv2 = (const float*)d_in[15];
  const float* Ws2 = (const float*)d_in[16];
  const float* g0  = (const float*)d_in[17];
  const float* b0  = (const float*)d_in[18];
  const int* src0 = (const int*)d_in[19];
  const int* dst0 = (const int*)d_in[20];
  const int* src1 = (const int*)d_in[21];
  const int* dst1 = (const int*)d_in[22];
  const int* src2 = (const int*)d_in[23];
  const int* dst2 = (const int*)d_in[24];
  const int* etyp = (const int*)d_in[25];

  float* ws = (float*)d_ws;

  // ---- workspace layout (float offsets); peak 29,826,896 floats = 113.8 MiB ----
  const size_t O_K1  = 0;          // 6.40M : acc0, then k1
  const size_t O_V1  = 6400000;    // 6.40M : v1
  const size_t O_Q1  = 12800000;   // 3.84M : q1
  const size_t O_LG1 = 16640000;   // 2.40M : per-edge logits/a (layer 1)
  const size_t O_M1  = 19040000;   // 240K  : segment max (ordered uint)
  const size_t O_SS1 = 19280000;   // 240K  : segment sum
  const size_t O_H2  = 19520000;   // 3.84M : s1 prefill + attention acc -> h2
  const size_t O_DEG = 23360000;   // 50K   : layer-0 degrees
  const size_t O_EK  = 23410000;   // 8320  : type_table @ Wek1
  const size_t O_EV  = 23418320;   // 8320  : attr_table @ Wev1
  const size_t O_BN  = 23426640;   // 256   : BN col sums/sumsq
  const size_t O_H1  = 23426896;   // 6.40M : h1
  // layer-2 overlays (over dead layer-1 regions, all < O_H2):
  const size_t O_K2  = 0;          // 3.84M
  const size_t O_V2  = 3840000;    // 3.84M
  const size_t O_Q2  = 7680000;    // 1.28M
  const size_t O_LG2 = 8960000;    // 800K
  const size_t O_M2  = 9760000;    // 80K
  const size_t O_SS2 = 9840000;    // 80K
  const size_t O_OUT2= 9920000;    // 1.28M : s2 prefill + attention acc

  // ================= layer 0 =================
  hipMemsetAsync(ws + O_K1, 0, (size_t)6400000 * 4, stream);   // acc0
  hipMemsetAsync(ws + O_DEG, 0, (size_t)50000 * 4, stream);    // deg
  hipMemsetAsync(ws + O_BN, 0, (size_t)256 * 4, stream);       // bn sums

  scatter0_kernel<<<(EE0 + 3) / 4, 256, 0, stream>>>(x, src0, dst0, ws + O_K1, ws + O_DEG);
  // h1 = 0.5 * (acc0 @ Wv0) / (deg + 1e-16)
  gemm128_kernel<<<(NN1 + 63) / 64, 256, 0, stream>>>(ws + O_K1, Wv0, ws + O_H1, NN1, ws + O_DEG);
  bn_stats_kernel<<<512, 256, 0, stream>>>(ws + O_H1, ws + O_BN);
  bn_apply_kernel<<<4096, 256, 0, stream>>>(ws + O_H1, ws + O_BN, g0, b0);

  // ================= layer 1 =================
  gemm128_kernel<<<(NN1 + 63) / 64, 256, 0, stream>>>(ws + O_H1, Wk1, ws + O_K1, NN1, nullptr);
  gemm128_kernel<<<(NN1 + 63) / 64, 256, 0, stream>>>(ws + O_H1, Wv1, ws + O_V1, NN1, nullptr);
  gemm128_kernel<<<(NN2 + 63) / 64, 256, 0, stream>>>(ws + O_H1, Wq1, ws + O_Q1, NN2, nullptr);
  gemm128_kernel<<<(NN2 + 63) / 64, 256, 0, stream>>>(ws + O_H1, Ws1, ws + O_H2, NN2, nullptr); // s1 prefill
  gemm128_kernel<<<2, 256, 0, stream>>>(tt, Wek1, ws + O_EK, 65, nullptr);
  gemm128_kernel<<<2, 256, 0, stream>>>(at, Wev1, ws + O_EV, 65, nullptr);

  hipMemsetAsync(ws + O_M1, 0, (size_t)480000 * 4, stream);    // M1 + SS1

  edge_logits_kernel<<<(EE1 + 3) / 4, 256, 0, stream>>>(
      ws + O_Q1, ws + O_K1, ws + O_EK, src1, dst1, etyp,
      ws + O_LG1, (unsigned*)(ws + O_M1), EE1);
  edge_exp_kernel<<<(EE1 * 8 + 255) / 256, 256, 0, stream>>>(
      ws + O_LG1, (const unsigned*)(ws + O_M1), ws + O_SS1, dst1, EE1);
  edge_accum_kernel<<<(EE1 + 3) / 4, 256, 0, stream>>>(
      ws + O_V1, ws + O_EV, src1, dst1, etyp, ws + O_LG1, ws + O_SS1, ws + O_H2, EE1);
  halve_kernel<<<7500, 256, 0, stream>>>(ws + O_H2, NN2 * DD);  // h2 = 0.5*(s1 + sum(alpha v))

  // ================= layer 2 =================
  gemm128_kernel<<<(NN2 + 63) / 64, 256, 0, stream>>>(ws + O_H2, Wk2, ws + O_K2, NN2, nullptr);
  gemm128_kernel<<<(NN2 + 63) / 64, 256, 0, stream>>>(ws + O_H2, Wv2, ws + O_V2, NN2, nullptr);
  gemm128_kernel<<<(NN3 + 63) / 64, 256, 0, stream>>>(ws + O_H2, Wq2, ws + O_Q2, NN3, nullptr);
  gemm128_kernel<<<(NN3 + 63) / 64, 256, 0, stream>>>(ws + O_H2, Ws2, ws + O_OUT2, NN3, nullptr); // s2 prefill

  hipMemsetAsync(ws + O_M2, 0, (size_t)160000 * 4, stream);    // M2 + SS2

  edge_logits_kernel<<<(EE2 + 3) / 4, 256, 0, stream>>>(
      ws + O_Q2, ws + O_K2, nullptr, src2, dst2, nullptr,
      ws + O_LG2, (unsigned*)(ws + O_M2), EE2);
  edge_exp_kernel<<<(EE2 * 8 + 255) / 256, 256, 0, stream>>>(
      ws + O_LG2, (const unsigned*)(ws + O_M2), ws + O_SS2, dst2, EE2);
  edge_accum_kernel<<<(EE2 + 3) / 4, 256, 0, stream>>>(
      ws + O_V2, nullptr, src2, dst2, nullptr, ws + O_LG2, ws + O_SS2, ws + O_OUT2, EE2);

  scale_out_kernel<<<2500, 256, 0, stream>>>(ws + O_OUT2, (float*)d_out, NN3 * DD);

  (void)in_sizes; (void)n_in; (void)out_size; (void)ws_size;
}

// Round 3
// 770.650 us; speedup vs baseline: 1.2172x; 1.2172x over previous
//
#include <hip/hip_runtime.h>
#include <math.h>

// ---------------- problem constants ----------------
#define DD 128
#define SPLIT 50000
#define NN1 50000
#define NN2 30000
#define NN3 10000
#define EE0 500000
#define EE1 300000
#define EE2 100000
#define NEG 0.2f

// ================= CSR build =================
__global__ __launch_bounds__(256) void hist_kernel(
    const int* __restrict__ dst, int* __restrict__ counts, int E)
{
  for (int e = blockIdx.x * 256 + threadIdx.x; e < E; e += gridDim.x * 256)
    atomicAdd(&counts[dst[e]], 1);
}

// inclusive scan of counts -> rp1[i] (=row_ptr+1), block totals -> partial
__global__ __launch_bounds__(256) void scan1_kernel(
    const int* __restrict__ counts, int* __restrict__ rp1,
    int* __restrict__ partial, int n)
{
  __shared__ int s[256];
  int t = threadIdx.x;
  int i = blockIdx.x * 256 + t;
  int v = (i < n) ? counts[i] : 0;
  s[t] = v; __syncthreads();
  for (int off = 1; off < 256; off <<= 1) {
    int tv = (t >= off) ? s[t - off] : 0;
    __syncthreads();
    s[t] += tv;
    __syncthreads();
  }
  if (i < n) rp1[i] = s[t];
  if (t == 255) partial[blockIdx.x] = s[255];
}

// exclusive scan of partials in place (single block; nb <= 256)
__global__ __launch_bounds__(256) void scan2_kernel(int* __restrict__ partial, int nb)
{
  __shared__ int s[256];
  int t = threadIdx.x;
  int v = (t < nb) ? partial[t] : 0;
  s[t] = v; __syncthreads();
  for (int off = 1; off < 256; off <<= 1) {
    int tv = (t >= off) ? s[t - off] : 0;
    __syncthreads();
    s[t] += tv;
    __syncthreads();
  }
  int ex = (t == 0) ? 0 : s[t - 1];
  if (t < nb) partial[t] = ex;
}

// rp1[i] += partial[i>>8]; row_ptr[0] = 0
__global__ __launch_bounds__(256) void scan3_kernel(
    int* __restrict__ rp /*row_ptr, length n+1*/, const int* __restrict__ partial, int n)
{
  int i = blockIdx.x * 256 + threadIdx.x;
  if (i < n) rp[i + 1] += partial[i >> 8];
  if (i == 0) rp[0] = 0;
}

// cursor pre-copied from row_ptr starts; scatter edge ids into slots
__global__ __launch_bounds__(256) void fill_kernel(
    const int* __restrict__ dst, int* __restrict__ cursor,
    int* __restrict__ eid, int E)
{
  for (int e = blockIdx.x * 256 + threadIdx.x; e < E; e += gridDim.x * 256) {
    int slot = atomicAdd(&cursor[dst[e]], 1);
    eid[slot] = e;
  }
}

// ================= layer 0: CSR gather-sum of x rows =================
__global__ __launch_bounds__(256) void agg0_kernel(
    const float* __restrict__ x, const int* __restrict__ src,
    const int* __restrict__ rp, const int* __restrict__ eid,
    float* __restrict__ acc, float* __restrict__ deg)
{
  int d = blockIdx.x * 4 + (threadIdx.x >> 6);
  if (d >= NN1) return;
  int lane = threadIdx.x & 63;
  int beg = rp[d], end = rp[d + 1];
  float a0 = 0.f, a1 = 0.f;
  for (int j = beg; j < end; ++j) {
    int s = src[eid[j]];
    if (s >= SPLIT) {
      const float* xp = x + (size_t)(s - SPLIT) * DD;
      a0 += xp[lane];
      a1 += xp[lane + 64];
    }
  }
  acc[(size_t)d * DD + lane] = a0;
  acc[(size_t)d * DD + lane + 64] = a1;
  if (lane == 0) deg[d] = (float)(end - beg);
}

// ---- C[N,128] = A[N,128] @ W[128,128]; deg!=null => *0.5/(deg+1e-16) ----
__global__ __launch_bounds__(256) void gemm128_kernel(
    const float* __restrict__ A, const float* __restrict__ W,
    float* __restrict__ C, int N, const float* __restrict__ deg)
{
  __shared__ float Al[64 * 128];
  __shared__ float Wl[64 * 128];
  int t = threadIdx.x;
  int cg = t & 31;
  int rg = t >> 5;
  int r0 = blockIdx.x << 6;
  int nrows = N - r0; if (nrows > 64) nrows = 64;

  const float4* Ag = (const float4*)(A + (size_t)r0 * DD);
  float4* Al4 = (float4*)Al;
  for (int i = t; i < nrows * 32; i += 256) Al4[i] = Ag[i];

  float acc[8][4] = {};
  const float4* W4 = (const float4*)W;
  float4* Wl4 = (float4*)Wl;
  const float4* Al4c = (const float4*)Al;

  for (int half = 0; half < 2; ++half) {
    __syncthreads();
    for (int i = t; i < 2048; i += 256) Wl4[i] = W4[half * 2048 + i];
    __syncthreads();
    const float4* Wl4c = (const float4*)Wl;
    int kb4 = half * 16;
    for (int k4 = 0; k4 < 16; ++k4) {
      float4 w0 = Wl4c[(k4 * 4 + 0) * 32 + cg];
      float4 w1 = Wl4c[(k4 * 4 + 1) * 32 + cg];
      float4 w2 = Wl4c[(k4 * 4 + 2) * 32 + cg];
      float4 w3 = Wl4c[(k4 * 4 + 3) * 32 + cg];
#pragma unroll
      for (int r = 0; r < 8; ++r) {
        float4 a = Al4c[(rg * 8 + r) * 32 + kb4 + k4];
        acc[r][0] = fmaf(a.x, w0.x, acc[r][0]);
        acc[r][1] = fmaf(a.x, w0.y, acc[r][1]);
        acc[r][2] = fmaf(a.x, w0.z, acc[r][2]);
        acc[r][3] = fmaf(a.x, w0.w, acc[r][3]);
        acc[r][0] = fmaf(a.y, w1.x, acc[r][0]);
        acc[r][1] = fmaf(a.y, w1.y, acc[r][1]);
        acc[r][2] = fmaf(a.y, w1.z, acc[r][2]);
        acc[r][3] = fmaf(a.y, w1.w, acc[r][3]);
        acc[r][0] = fmaf(a.z, w2.x, acc[r][0]);
        acc[r][1] = fmaf(a.z, w2.y, acc[r][1]);
        acc[r][2] = fmaf(a.z, w2.z, acc[r][2]);
        acc[r][3] = fmaf(a.z, w2.w, acc[r][3]);
        acc[r][0] = fmaf(a.w, w3.x, acc[r][0]);
        acc[r][1] = fmaf(a.w, w3.y, acc[r][1]);
        acc[r][2] = fmaf(a.w, w3.z, acc[r][2]);
        acc[r][3] = fmaf(a.w, w3.w, acc[r][3]);
      }
    }
  }

#pragma unroll
  for (int r = 0; r < 8; ++r) {
    int rr = rg * 8 + r;
    if (rr < nrows) {
      float sc = 1.0f;
      if (deg) sc = 0.5f / (deg[r0 + rr] + 1e-16f);
      float4 o;
      o.x = acc[r][0] * sc; o.y = acc[r][1] * sc;
      o.z = acc[r][2] * sc; o.w = acc[r][3] * sc;
      ((float4*)(C + (size_t)(r0 + rr) * DD))[cg] = o;
    }
  }
}

// ---------------- BatchNorm ----------------
__global__ __launch_bounds__(256) void bn_stats_kernel(
    const float* __restrict__ H, float* __restrict__ sums)
{
  int t = threadIdx.x;
  int col = t & 127;
  float s = 0.f, q = 0.f;
  for (int r = blockIdx.x * 2 + (t >> 7); r < NN1; r += gridDim.x * 2) {
    float v = H[(size_t)r * DD + col];
    s += v; q += v * v;
  }
  __shared__ float ls[256], lq[256];
  ls[t] = s; lq[t] = q;
  __syncthreads();
  if (t < 128) {
    atomicAdd(&sums[col], ls[t] + ls[t + 128]);
    atomicAdd(&sums[128 + col], lq[t] + lq[t + 128]);
  }
}

__global__ __launch_bounds__(256) void bn_apply_kernel(
    float* __restrict__ H, const float* __restrict__ sums,
    const float* __restrict__ g, const float* __restrict__ b)
{
  const float invN = 1.0f / (float)NN1;
  size_t total = (size_t)NN1 * DD;
  for (size_t i = (size_t)blockIdx.x * 256 + threadIdx.x; i < total;
       i += (size_t)gridDim.x * 256) {
    int col = (int)(i & 127);
    float mu = sums[col] * invN;
    float var = sums[128 + col] * invN - mu * mu;
    float rs = rsqrtf(var + 1e-5f);
    H[i] = (H[i] - mu) * rs * g[col] + b[col];
  }
}

// ========== fused flash-attention over CSR: out = 0.5*(Spre + softmax-agg) ==========
__global__ __launch_bounds__(256) void attn_kernel(
    const float* __restrict__ Q, const float* __restrict__ K,
    const float* __restrict__ V, const float* __restrict__ EKT,
    const float* __restrict__ EVT, const int* __restrict__ srcArr,
    const int* __restrict__ et, const int* __restrict__ rp,
    const int* __restrict__ eid, const float* __restrict__ Spre,
    float* __restrict__ Out, int Nt)
{
  int d = blockIdx.x * 4 + (threadIdx.x >> 6);
  if (d >= Nt) return;
  int lane = threadIdx.x & 63;

  float q0 = Q[(size_t)d * DD + lane];
  float q1 = Q[(size_t)d * DD + lane + 64];

  float m0 = -INFINITY, m1 = -INFINITY;
  float s0 = 0.f, s1 = 0.f;
  float o0 = 0.f, o1 = 0.f;

  int beg = rp[d], end = rp[d + 1];
  for (int j = beg; j < end; ++j) {
    int e = eid[j];
    int s = srcArr[e];
    const float* kp = K + (size_t)s * DD;
    float k0 = kp[lane], k1 = kp[lane + 64];
    const float* vp = V + (size_t)s * DD;
    float v0 = vp[lane], v1 = vp[lane + 64];
    if (EKT) {
      int ty = et[e];
      const float* ek = EKT + (size_t)ty * DD;
      k0 += ek[lane]; k1 += ek[lane + 64];
      const float* ev = EVT + (size_t)ty * DD;
      v0 += ev[lane]; v1 += ev[lane + 64];
    }
    float p0 = q0 * k0, p1 = q1 * k1;
#pragma unroll
    for (int off = 8; off >= 1; off >>= 1) {
      p0 += __shfl_xor(p0, off);
      p1 += __shfl_xor(p1, off);
    }
    // all lanes in each 16-lane group now hold dot for head (lane>>4) / 4+(lane>>4)
    float l0 = p0 * 0.25f; l0 = (l0 >= 0.f) ? l0 : NEG * l0;
    float l1 = p1 * 0.25f; l1 = (l1 >= 0.f) ? l1 : NEG * l1;

    float nm0 = fmaxf(m0, l0);
    float w0 = __expf(m0 - nm0);        // exp(-inf)=0 on first edge
    float a0 = __expf(l0 - nm0);
    s0 = s0 * w0 + a0;
    o0 = o0 * w0 + a0 * v0;
    m0 = nm0;

    float nm1 = fmaxf(m1, l1);
    float w1 = __expf(m1 - nm1);
    float a1 = __expf(l1 - nm1);
    s1 = s1 * w1 + a1;
    o1 = o1 * w1 + a1 * v1;
    m1 = nm1;
  }

  float r0 = Spre[(size_t)d * DD + lane];
  float r1 = Spre[(size_t)d * DD + lane + 64];
  Out[(size_t)d * DD + lane]      = 0.5f * (r0 + o0 / (s0 + 1e-16f));
  Out[(size_t)d * DD + lane + 64] = 0.5f * (r1 + o1 / (s1 + 1e-16f));
}

extern "C" void kernel_launch(void* const* d_in, const int* in_sizes, int n_in,
                              void* d_out, int out_size, void* d_ws, size_t ws_size,
                              hipStream_t stream)
{
  const float* x   = (const float*)d_in[0];
  const float* tt  = (const float*)d_in[1];
  const float* at  = (const float*)d_in[2];
  const float* Wv0 = (const float*)d_in[5];
  const float* Wq1 = (const float*)d_in[7];
  const float* Wk1 = (const float*)d_in[8];
  const float* Wv1 = (const float*)d_in[9];
  const float* Ws1 = (const float*)d_in[10];
  const float* Wek1= (const float*)d_in[11];
  const float* Wev1= (const float*)d_in[12];
  const float* Wq2 = (const float*)d_in[13];
  const float* Wk2 = (const float*)d_in[14];
  const float* Wv2 = (const float*)d_in[15];
  const float* Ws2 = (const float*)d_in[16];
  const float* g0  = (const float*)d_in[17];
  const float* b0  = (const float*)d_in[18];
  const int* src0 = (const int*)d_in[19];
  const int* dst0 = (const int*)d_in[20];
  const int* src1 = (const int*)d_in[21];
  const int* dst1 = (const int*)d_in[22];
  const int* src2 = (const int*)d_in[23];
  const int* dst2 = (const int*)d_in[24];
  const int* etyp = (const int*)d_in[25];

  float* ws = (float*)d_ws;

  // ---- float workspace layout (float offsets); end 26,946,896 fl ----
  const size_t O_K1  = 0;          // 6.40M : acc0, then k1
  const size_t O_V1  = 6400000;    // 6.40M : v1
  const size_t O_Q1  = 12800000;   // 3.84M : q1
  const size_t O_H2  = 16640000;   // 3.84M : s1 prefill -> h2 (attn writes in place)
  const size_t O_DEG = 20480000;   // 50K
  const size_t O_EK  = 20530000;   // 8320
  const size_t O_EV  = 20538320;   // 8320
  const size_t O_BN  = 20546640;   // 256
  const size_t O_H1  = 20546896;   // 6.40M
  // layer-2 overlays (dead layer-1 regions):
  const size_t O_K2  = 0;          // 3.84M
  const size_t O_V2  = 3840000;    // 3.84M
  const size_t O_Q2  = 7680000;    // 1.28M
  const size_t O_S2  = 8960000;    // 1.28M : s2 prefill
  // ---- int workspace after float region ----
  int* wi = (int*)(ws + 26946896);
  int* RP0  = wi;                 // 50001
  int* RP1  = wi + 50001;         // 30001
  int* RP2  = wi + 80002;         // 10001
  int* EID0 = wi + 90003;         // 500000
  int* EID1 = wi + 590003;        // 300000
  int* EID2 = wi + 890003;        // 100000
  int* CNT  = wi + 990003;        // 50000 (reused)
  int* CUR  = wi + 1040003;       // 50000 (reused)
  int* PART = wi + 1090003;       // 256

  // ---- build CSR for one edge list ----
  auto build_csr = [&](const int* dst, int E, int Nt, int* rp, int* eidb) {
    hipMemsetAsync(CNT, 0, (size_t)Nt * 4, stream);
    hist_kernel<<<(E + 255) / 256, 256, 0, stream>>>(dst, CNT, E);
    int nb = (Nt + 255) / 256;
    scan1_kernel<<<nb, 256, 0, stream>>>(CNT, rp + 1, PART, Nt);
    scan2_kernel<<<1, 256, 0, stream>>>(PART, nb);
    scan3_kernel<<<nb, 256, 0, stream>>>(rp, PART, Nt);
    hipMemcpyAsync(CUR, rp, (size_t)Nt * 4, hipMemcpyDeviceToDevice, stream);
    fill_kernel<<<(E + 255) / 256, 256, 0, stream>>>(dst, CUR, eidb, E);
  };

  // ================= CSR builds =================
  build_csr(dst0, EE0, NN1, RP0, EID0);
  build_csr(dst1, EE1, NN2, RP1, EID1);
  build_csr(dst2, EE2, NN3, RP2, EID2);

  hipMemsetAsync(ws + O_BN, 0, (size_t)256 * 4, stream);

  // ================= layer 0 =================
  agg0_kernel<<<(NN1 + 3) / 4, 256, 0, stream>>>(x, src0, RP0, EID0, ws + O_K1, ws + O_DEG);
  gemm128_kernel<<<(NN1 + 63) / 64, 256, 0, stream>>>(ws + O_K1, Wv0, ws + O_H1, NN1, ws + O_DEG);
  bn_stats_kernel<<<512, 256, 0, stream>>>(ws + O_H1, ws + O_BN);
  bn_apply_kernel<<<4096, 256, 0, stream>>>(ws + O_H1, ws + O_BN, g0, b0);

  // ================= layer 1 =================
  gemm128_kernel<<<(NN1 + 63) / 64, 256, 0, stream>>>(ws + O_H1, Wk1, ws + O_K1, NN1, nullptr);
  gemm128_kernel<<<(NN1 + 63) / 64, 256, 0, stream>>>(ws + O_H1, Wv1, ws + O_V1, NN1, nullptr);
  gemm128_kernel<<<(NN2 + 63) / 64, 256, 0, stream>>>(ws + O_H1, Wq1, ws + O_Q1, NN2, nullptr);
  gemm128_kernel<<<(NN2 + 63) / 64, 256, 0, stream>>>(ws + O_H1, Ws1, ws + O_H2, NN2, nullptr);
  gemm128_kernel<<<2, 256, 0, stream>>>(tt, Wek1, ws + O_EK, 65, nullptr);
  gemm128_kernel<<<2, 256, 0, stream>>>(at, Wev1, ws + O_EV, 65, nullptr);

  attn_kernel<<<(NN2 + 3) / 4, 256, 0, stream>>>(
      ws + O_Q1, ws + O_K1, ws + O_V1, ws + O_EK, ws + O_EV,
      src1, etyp, RP1, EID1, ws + O_H2, ws + O_H2, NN2);

  // ================= layer 2 =================
  gemm128_kernel<<<(NN2 + 63) / 64, 256, 0, stream>>>(ws + O_H2, Wk2, ws + O_K2, NN2, nullptr);
  gemm128_kernel<<<(NN2 + 63) / 64, 256, 0, stream>>>(ws + O_H2, Wv2, ws + O_V2, NN2, nullptr);
  gemm128_kernel<<<(NN3 + 63) / 64, 256, 0, stream>>>(ws + O_H2, Wq2, ws + O_Q2, NN3, nullptr);
  gemm128_kernel<<<(NN3 + 63) / 64, 256, 0, stream>>>(ws + O_H2, Ws2, ws + O_S2, NN3, nullptr);

  attn_kernel<<<(NN3 + 3) / 4, 256, 0, stream>>>(
      ws + O_Q2, ws + O_K2, ws + O_V2, nullptr, nullptr,
      src2, nullptr, RP2, EID2, ws + O_S2, (float*)d_out, NN3);

  (void)in_sizes; (void)n_in; (void)out_size; (void)ws_size;
}

// Round 4
// 600.349 us; speedup vs baseline: 1.5625x; 1.2837x over previous
//
#include <hip/hip_runtime.h>
#include <math.h>

// ---------------- problem constants ----------------
#define DD 128
#define SPLIT 50000
#define NN1 50000
#define NN2 30000
#define NN3 10000
#define EE0 500000
#define EE1 300000
#define EE2 100000
#define EALL (EE0 + EE1 + EE2)
#define NALL (NN1 + NN2 + NN3)   // 90000
#define B1 50000                  // count-array base of graph1
#define B2 80000                  // count-array base of graph2
#define NEG 0.2f

// ================= fused CSR build (3 graphs concatenated) =================
__global__ __launch_bounds__(256) void hist_kernel(
    const int* __restrict__ dst0, const int* __restrict__ dst1,
    const int* __restrict__ dst2, int* __restrict__ counts)
{
  for (int e = blockIdx.x * 256 + threadIdx.x; e < EALL; e += gridDim.x * 256) {
    int d;
    if (e < EE0) d = dst0[e];
    else if (e < EE0 + EE1) d = B1 + dst1[e - EE0];
    else d = B2 + dst2[e - EE0 - EE1];
    atomicAdd(&counts[d], 1);
  }
}

// inclusive scan per 256-block: counts -> rp1 (=row_ptr+1), block totals -> partial
__global__ __launch_bounds__(256) void scan1_kernel(
    const int* __restrict__ counts, int* __restrict__ rp1,
    int* __restrict__ partial, int n)
{
  __shared__ int s[256];
  int t = threadIdx.x;
  int i = blockIdx.x * 256 + t;
  int v = (i < n) ? counts[i] : 0;
  s[t] = v; __syncthreads();
  for (int off = 1; off < 256; off <<= 1) {
    int tv = (t >= off) ? s[t - off] : 0;
    __syncthreads();
    s[t] += tv;
    __syncthreads();
  }
  if (i < n) rp1[i] = s[t];
  if (t == 255) partial[blockIdx.x] = s[255];
}

// exclusive scan of partials in place (single block, loop-carried; nb any)
__global__ __launch_bounds__(256) void scan2_kernel(int* __restrict__ partial, int nb)
{
  __shared__ int s[256];
  int t = threadIdx.x;
  int carry = 0;
  for (int base = 0; base < nb; base += 256) {
    int i = base + t;
    int v = (i < nb) ? partial[i] : 0;
    s[t] = v; __syncthreads();
    for (int off = 1; off < 256; off <<= 1) {
      int tv = (t >= off) ? s[t - off] : 0;
      __syncthreads();
      s[t] += tv;
      __syncthreads();
    }
    int ex = carry + ((t == 0) ? 0 : s[t - 1]);
    if (i < nb) partial[i] = ex;
    int tot = s[255];
    __syncthreads();
    carry += tot;
  }
}

// rp[i+1] += partial[i>>8]; rp[0] = 0
__global__ __launch_bounds__(256) void scan3_kernel(
    int* __restrict__ rp, const int* __restrict__ partial, int n)
{
  int i = blockIdx.x * 256 + threadIdx.x;
  if (i < n) rp[i + 1] += partial[i >> 8];
  if (i == 0) rp[0] = 0;
}

// scatter CSR values: graph0/2 -> src, graph1 -> src | (etype<<17)
__global__ __launch_bounds__(256) void fill_kernel(
    const int* __restrict__ dst0, const int* __restrict__ src0,
    const int* __restrict__ dst1, const int* __restrict__ src1,
    const int* __restrict__ dst2, const int* __restrict__ src2,
    const int* __restrict__ etyp, int* __restrict__ cursor,
    int* __restrict__ vals)
{
  for (int e = blockIdx.x * 256 + threadIdx.x; e < EALL; e += gridDim.x * 256) {
    int d, v;
    if (e < EE0) { d = dst0[e]; v = src0[e]; }
    else if (e < EE0 + EE1) {
      int k = e - EE0;
      d = B1 + dst1[k]; v = src1[k] | (etyp[k] << 17);
    } else {
      int k = e - EE0 - EE1;
      d = B2 + dst2[k]; v = src2[k];
    }
    int slot = atomicAdd(&cursor[d], 1);
    vals[slot] = v;
  }
}

// ================= layer 0: CSR gather-sum of x rows (float4, 2 edges/wave) ==========
__global__ __launch_bounds__(256) void agg0_kernel(
    const float* __restrict__ x, const int* __restrict__ rp,
    const int* __restrict__ vals, float* __restrict__ acc, float* __restrict__ deg)
{
  int d = blockIdx.x * 4 + (threadIdx.x >> 6);
  if (d >= NN1) return;
  int lane = threadIdx.x & 63;
  int l32 = lane & 31, half = lane >> 5;
  int beg = rp[d], end = rp[d + 1];
  const float4* x4 = (const float4*)x;
  float4 a0 = {0.f, 0.f, 0.f, 0.f}, a1 = {0.f, 0.f, 0.f, 0.f};
  int j = beg + half;
  for (; j + 2 < end; j += 4) {
    int s0 = vals[j], s1 = vals[j + 2];
    if (s0 >= SPLIT) {
      float4 v = x4[(size_t)(s0 - SPLIT) * 32 + l32];
      a0.x += v.x; a0.y += v.y; a0.z += v.z; a0.w += v.w;
    }
    if (s1 >= SPLIT) {
      float4 v = x4[(size_t)(s1 - SPLIT) * 32 + l32];
      a1.x += v.x; a1.y += v.y; a1.z += v.z; a1.w += v.w;
    }
  }
  if (j < end) {
    int s0 = vals[j];
    if (s0 >= SPLIT) {
      float4 v = x4[(size_t)(s0 - SPLIT) * 32 + l32];
      a0.x += v.x; a0.y += v.y; a0.z += v.z; a0.w += v.w;
    }
  }
  a0.x += a1.x; a0.y += a1.y; a0.z += a1.z; a0.w += a1.w;
  // merge halves: lanes<32 pull partner lane+32
  a0.x += __shfl(a0.x, l32 + 32);
  a0.y += __shfl(a0.y, l32 + 32);
  a0.z += __shfl(a0.z, l32 + 32);
  a0.w += __shfl(a0.w, l32 + 32);
  if (half == 0) {
    ((float4*)acc)[(size_t)d * 32 + l32] = a0;
    if (l32 == 0) deg[d] = (float)(end - beg);
  }
}

// ---- single-output C[N,128] = A @ W; deg!=null => *0.5/(deg+1e-16) ----
__global__ __launch_bounds__(256) void gemm128_kernel(
    const float* __restrict__ A, const float* __restrict__ W,
    float* __restrict__ C, int N, const float* __restrict__ deg)
{
  __shared__ float Al[64 * 128];
  __shared__ float Wl[64 * 128];
  int t = threadIdx.x;
  int cg = t & 31;
  int rg = t >> 5;
  int r0 = blockIdx.x << 6;
  int nrows = N - r0; if (nrows > 64) nrows = 64;

  const float4* Ag = (const float4*)(A + (size_t)r0 * DD);
  float4* Al4 = (float4*)Al;
  for (int i = t; i < nrows * 32; i += 256) Al4[i] = Ag[i];

  float acc[8][4] = {};
  const float4* W4 = (const float4*)W;
  float4* Wl4 = (float4*)Wl;
  const float4* Al4c = (const float4*)Al;

  for (int half = 0; half < 2; ++half) {
    __syncthreads();
    for (int i = t; i < 2048; i += 256) Wl4[i] = W4[half * 2048 + i];
    __syncthreads();
    const float4* Wl4c = (const float4*)Wl;
    int kb4 = half * 16;
    for (int k4 = 0; k4 < 16; ++k4) {
      float4 w0 = Wl4c[(k4 * 4 + 0) * 32 + cg];
      float4 w1 = Wl4c[(k4 * 4 + 1) * 32 + cg];
      float4 w2 = Wl4c[(k4 * 4 + 2) * 32 + cg];
      float4 w3 = Wl4c[(k4 * 4 + 3) * 32 + cg];
#pragma unroll
      for (int r = 0; r < 8; ++r) {
        float4 a = Al4c[(rg * 8 + r) * 32 + kb4 + k4];
        acc[r][0] = fmaf(a.x, w0.x, acc[r][0]);
        acc[r][1] = fmaf(a.x, w0.y, acc[r][1]);
        acc[r][2] = fmaf(a.x, w0.z, acc[r][2]);
        acc[r][3] = fmaf(a.x, w0.w, acc[r][3]);
        acc[r][0] = fmaf(a.y, w1.x, acc[r][0]);
        acc[r][1] = fmaf(a.y, w1.y, acc[r][1]);
        acc[r][2] = fmaf(a.y, w1.z, acc[r][2]);
        acc[r][3] = fmaf(a.y, w1.w, acc[r][3]);
        acc[r][0] = fmaf(a.z, w2.x, acc[r][0]);
        acc[r][1] = fmaf(a.z, w2.y, acc[r][1]);
        acc[r][2] = fmaf(a.z, w2.z, acc[r][2]);
        acc[r][3] = fmaf(a.z, w2.w, acc[r][3]);
        acc[r][0] = fmaf(a.w, w3.x, acc[r][0]);
        acc[r][1] = fmaf(a.w, w3.y, acc[r][1]);
        acc[r][2] = fmaf(a.w, w3.z, acc[r][2]);
        acc[r][3] = fmaf(a.w, w3.w, acc[r][3]);
      }
    }
  }

#pragma unroll
  for (int r = 0; r < 8; ++r) {
    int rr = rg * 8 + r;
    if (rr < nrows) {
      float sc = 1.0f;
      if (deg) sc = 0.5f / (deg[r0 + rr] + 1e-16f);
      float4 o;
      o.x = acc[r][0] * sc; o.y = acc[r][1] * sc;
      o.z = acc[r][2] * sc; o.w = acc[r][3] * sc;
      ((float4*)(C + (size_t)(r0 + rr) * DD))[cg] = o;
    }
  }
}

// ---- fused 4-output GEMM: Ci = bn(A) @ Wi. N0 must be the max Ni. ----
__global__ __launch_bounds__(256) void gemm4_kernel(
    const float* __restrict__ A, const float* __restrict__ SC,
    const float* __restrict__ SH,
    const float* __restrict__ W0, float* __restrict__ C0, int N0,
    const float* __restrict__ W1, float* __restrict__ C1, int N1,
    const float* __restrict__ W2, float* __restrict__ C2, int N2,
    const float* __restrict__ W3, float* __restrict__ C3, int N3)
{
  __shared__ float Al[64 * 128];
  __shared__ float Wl[64 * 128];
  int t = threadIdx.x;
  int cg = t & 31;
  int rg = t >> 5;
  int r0 = blockIdx.x << 6;
  int nrows = N0 - r0; if (nrows > 64) nrows = 64;

  const float4* Ag = (const float4*)(A + (size_t)r0 * DD);
  float4* Al4 = (float4*)Al;
  if (SC) {
    const float4* SC4 = (const float4*)SC;
    const float4* SH4 = (const float4*)SH;
    for (int i = t; i < nrows * 32; i += 256) {
      float4 a = Ag[i];
      float4 sc = SC4[i & 31], sh = SH4[i & 31];
      a.x = fmaf(a.x, sc.x, sh.x);
      a.y = fmaf(a.y, sc.y, sh.y);
      a.z = fmaf(a.z, sc.z, sh.z);
      a.w = fmaf(a.w, sc.w, sh.w);
      Al4[i] = a;
    }
  } else {
    for (int i = t; i < nrows * 32; i += 256) Al4[i] = Ag[i];
  }

  const float* Ws[4] = {W0, W1, W2, W3};
  float* Cs[4] = {C0, C1, C2, C3};
  int Ns[4] = {N0, N1, N2, N3};
  const float4* Al4c = (const float4*)Al;
  float4* Wl4 = (float4*)Wl;

#pragma unroll
  for (int o = 0; o < 4; ++o) {
    if (r0 >= Ns[o]) continue;     // uniform within block
    int nr = Ns[o] - r0; if (nr > 64) nr = 64;
    float acc[8][4] = {};
    const float4* W4 = (const float4*)Ws[o];
    for (int half = 0; half < 2; ++half) {
      __syncthreads();
      for (int i = t; i < 2048; i += 256) Wl4[i] = W4[half * 2048 + i];
      __syncthreads();
      const float4* Wl4c = (const float4*)Wl;
      int kb4 = half * 16;
      for (int k4 = 0; k4 < 16; ++k4) {
        float4 w0 = Wl4c[(k4 * 4 + 0) * 32 + cg];
        float4 w1 = Wl4c[(k4 * 4 + 1) * 32 + cg];
        float4 w2 = Wl4c[(k4 * 4 + 2) * 32 + cg];
        float4 w3 = Wl4c[(k4 * 4 + 3) * 32 + cg];
#pragma unroll
        for (int r = 0; r < 8; ++r) {
          float4 a = Al4c[(rg * 8 + r) * 32 + kb4 + k4];
          acc[r][0] = fmaf(a.x, w0.x, acc[r][0]);
          acc[r][1] = fmaf(a.x, w0.y, acc[r][1]);
          acc[r][2] = fmaf(a.x, w0.z, acc[r][2]);
          acc[r][3] = fmaf(a.x, w0.w, acc[r][3]);
          acc[r][0] = fmaf(a.y, w1.x, acc[r][0]);
          acc[r][1] = fmaf(a.y, w1.y, acc[r][1]);
          acc[r][2] = fmaf(a.y, w1.z, acc[r][2]);
          acc[r][3] = fmaf(a.y, w1.w, acc[r][3]);
          acc[r][0] = fmaf(a.z, w2.x, acc[r][0]);
          acc[r][1] = fmaf(a.z, w2.y, acc[r][1]);
          acc[r][2] = fmaf(a.z, w2.z, acc[r][2]);
          acc[r][3] = fmaf(a.z, w2.w, acc[r][3]);
          acc[r][0] = fmaf(a.w, w3.x, acc[r][0]);
          acc[r][1] = fmaf(a.w, w3.y, acc[r][1]);
          acc[r][2] = fmaf(a.w, w3.z, acc[r][2]);
          acc[r][3] = fmaf(a.w, w3.w, acc[r][3]);
        }
      }
    }
#pragma unroll
    for (int r = 0; r < 8; ++r) {
      int rr = rg * 8 + r;
      if (rr < nr) {
        float4 ov;
        ov.x = acc[r][0]; ov.y = acc[r][1]; ov.z = acc[r][2]; ov.w = acc[r][3];
        ((float4*)(Cs[o] + (size_t)(r0 + rr) * DD))[cg] = ov;
      }
    }
  }
}

// ---------------- BatchNorm stats + finalize ----------------
__global__ __launch_bounds__(256) void bn_stats_kernel(
    const float* __restrict__ H, float* __restrict__ sums)
{
  int t = threadIdx.x;
  int col = t & 127;
  float s = 0.f, q = 0.f;
  for (int r = blockIdx.x * 2 + (t >> 7); r < NN1; r += gridDim.x * 2) {
    float v = H[(size_t)r * DD + col];
    s += v; q += v * v;
  }
  __shared__ float ls[256], lq[256];
  ls[t] = s; lq[t] = q;
  __syncthreads();
  if (t < 128) {
    atomicAdd(&sums[col], ls[t] + ls[t + 128]);
    atomicAdd(&sums[128 + col], lq[t] + lq[t + 128]);
  }
}

__global__ __launch_bounds__(128) void bn_finalize_kernel(
    const float* __restrict__ sums, const float* __restrict__ g,
    const float* __restrict__ b, float* __restrict__ SC, float* __restrict__ SH)
{
  int c = threadIdx.x;
  const float invN = 1.0f / (float)NN1;
  float mu = sums[c] * invN;
  float var = sums[128 + c] * invN - mu * mu;
  float rs = rsqrtf(var + 1e-5f);
  float sc = rs * g[c];
  SC[c] = sc;
  SH[c] = b[c] - mu * sc;
}

// ========== fused flash-attention over value-CSR (float4 lanes, 2 edges/wave) ==========
// out = 0.5*(Spre + softmax-agg). EKT!=null => vals packed src|(et<<17).
__global__ __launch_bounds__(256) void attn_kernel(
    const float* __restrict__ Q, const float* __restrict__ K,
    const float* __restrict__ V, const float* __restrict__ EKT,
    const float* __restrict__ EVT, const int* __restrict__ rp,
    const int* __restrict__ vals, const float* __restrict__ Spre,
    float* __restrict__ Out, int Nt)
{
  int d = blockIdx.x * 4 + (threadIdx.x >> 6);
  if (d >= Nt) return;
  int lane = threadIdx.x & 63;
  int l32 = lane & 31, half = lane >> 5;

  const float4* Q4 = (const float4*)Q;
  const float4* K4 = (const float4*)K;
  const float4* V4 = (const float4*)V;
  float4 q = Q4[(size_t)d * 32 + l32];

  float m = -INFINITY, ss = 0.f;
  float4 o = {0.f, 0.f, 0.f, 0.f};

  int beg = rp[d], end = rp[d + 1];
  for (int j = beg + half; j < end; j += 2) {
    int pv = vals[j];
    float4 kk, vv;
    if (EKT) {
      int s = pv & 0x1FFFF, ty = pv >> 17;
      kk = K4[(size_t)s * 32 + l32];
      vv = V4[(size_t)s * 32 + l32];
      float4 ek = ((const float4*)EKT)[(size_t)ty * 32 + l32];
      float4 ev = ((const float4*)EVT)[(size_t)ty * 32 + l32];
      kk.x += ek.x; kk.y += ek.y; kk.z += ek.z; kk.w += ek.w;
      vv.x += ev.x; vv.y += ev.y; vv.z += ev.z; vv.w += ev.w;
    } else {
      kk = K4[(size_t)pv * 32 + l32];
      vv = V4[(size_t)pv * 32 + l32];
    }
    float p = q.x * kk.x + q.y * kk.y + q.z * kk.z + q.w * kk.w;
    p += __shfl_xor(p, 1);
    p += __shfl_xor(p, 2);          // 4-lane head group -> full 16-dim dot
    float l = p * 0.25f;
    l = (l >= 0.f) ? l : NEG * l;
    float nm = fmaxf(m, l);
    float w = __expf(m - nm);       // first edge: exp(-inf)=0
    float a = __expf(l - nm);
    ss = ss * w + a;
    o.x = o.x * w + a * vv.x;
    o.y = o.y * w + a * vv.y;
    o.z = o.z * w + a * vv.z;
    o.w = o.w * w + a * vv.w;
    m = nm;
  }

  // merge the two half-wave states (flash merge)
  float mp = __shfl_xor(m, 32);
  float sp = __shfl_xor(ss, 32);
  float4 op;
  op.x = __shfl_xor(o.x, 32);
  op.y = __shfl_xor(o.y, 32);
  op.z = __shfl_xor(o.z, 32);
  op.w = __shfl_xor(o.w, 32);
  float nm = fmaxf(m, mp);
  if (nm == -INFINITY) nm = 0.f;    // target with zero edges
  float w = __expf(m - nm);
  float wp = __expf(mp - nm);
  float sT = ss * w + sp * wp;
  float inv = 1.0f / (sT + 1e-16f);
  float4 res;
  res.x = (o.x * w + op.x * wp) * inv;
  res.y = (o.y * w + op.y * wp) * inv;
  res.z = (o.z * w + op.z * wp) * inv;
  res.w = (o.w * w + op.w * wp) * inv;

  if (half == 0) {
    float4 sr = ((const float4*)Spre)[(size_t)d * 32 + l32];
    float4 ot;
    ot.x = 0.5f * (sr.x + res.x);
    ot.y = 0.5f * (sr.y + res.y);
    ot.z = 0.5f * (sr.z + res.z);
    ot.w = 0.5f * (sr.w + res.w);
    ((float4*)Out)[(size_t)d * 32 + l32] = ot;
  }
}

extern "C" void kernel_launch(void* const* d_in, const int* in_sizes, int n_in,
                              void* d_out, int out_size, void* d_ws, size_t ws_size,
                              hipStream_t stream)
{
  const float* x   = (const float*)d_in[0];
  const float* tt  = (const float*)d_in[1];
  const float* at  = (const float*)d_in[2];
  const float* Wv0 = (const float*)d_in[5];
  const float* Wq1 = (const float*)d_in[7];
  const float* Wk1 = (const float*)d_in[8];
  const float* Wv1 = (const float*)d_in[9];
  const float* Ws1 = (const float*)d_in[10];
  const float* Wek1= (const float*)d_in[11];
  const float* Wev1= (const float*)d_in[12];
  const float* Wq2 = (const float*)d_in[13];
  const float* Wk2 = (const float*)d_in[14];
  const float* Wv2 = (const float*)d_in[15];
  const float* Ws2 = (const float*)d_in[16];
  const float* g0  = (const float*)d_in[17];
  const float* b0  = (const float*)d_in[18];
  const int* src0 = (const int*)d_in[19];
  const int* dst0 = (const int*)d_in[20];
  const int* src1 = (const int*)d_in[21];
  const int* dst1 = (const int*)d_in[22];
  const int* src2 = (const int*)d_in[23];
  const int* dst2 = (const int*)d_in[24];
  const int* etyp = (const int*)d_in[25];

  float* ws = (float*)d_ws;

  // ---- float workspace layout (float offsets) ----
  const size_t O_K1  = 0;          // 6.40M : acc0, then k1
  const size_t O_V1  = 6400000;    // 6.40M : v1
  const size_t O_Q1  = 12800000;   // 3.84M : q1
  const size_t O_H2  = 16640000;   // 3.84M : s1 prefill -> h2 (attn in place)
  const size_t O_DEG = 20480000;   // 50K
  const size_t O_EK  = 20530000;   // 8320
  const size_t O_EV  = 20538320;   // 8320
  const size_t O_BN  = 20546640;   // 256
  const size_t O_SC  = 20546896;   // 128
  const size_t O_SH  = 20547024;   // 128
  const size_t O_H1  = 20547152;   // 6.40M -> end 26,947,152
  // layer-2 overlays (dead layer-1 regions):
  const size_t O_K2  = 0;          // 3.84M
  const size_t O_V2  = 3840000;    // 3.84M
  const size_t O_Q2  = 7680000;    // 1.28M
  const size_t O_S2  = 8960000;    // 1.28M
  // ---- int workspace ----
  int* wi   = (int*)(ws + 26947152);
  int* RP   = wi;                  // 90001 (concat row_ptr; graph bases 0/B1/B2)
  int* VALS = wi + 90001;          // 900000
  int* CNT  = wi + 990001;         // 90000 (histogram, then cursor)
  int* PART = wi + 1080001;        // 512

  // ================= fused CSR build =================
  hipMemsetAsync(CNT, 0, (size_t)NALL * 4, stream);
  hist_kernel<<<3516, 256, 0, stream>>>(dst0, dst1, dst2, CNT);
  int nb = (NALL + 255) / 256;     // 352
  scan1_kernel<<<nb, 256, 0, stream>>>(CNT, RP + 1, PART, NALL);
  scan2_kernel<<<1, 256, 0, stream>>>(PART, nb);
  scan3_kernel<<<nb, 256, 0, stream>>>(RP, PART, NALL);
  hipMemcpyAsync(CNT, RP, (size_t)NALL * 4, hipMemcpyDeviceToDevice, stream); // cursor
  fill_kernel<<<3516, 256, 0, stream>>>(dst0, src0, dst1, src1, dst2, src2,
                                        etyp, CNT, VALS);

  hipMemsetAsync(ws + O_BN, 0, (size_t)256 * 4, stream);

  // ================= layer 0 =================
  agg0_kernel<<<(NN1 + 3) / 4, 256, 0, stream>>>(x, RP, VALS, ws + O_K1, ws + O_DEG);
  gemm128_kernel<<<(NN1 + 63) / 64, 256, 0, stream>>>(ws + O_K1, Wv0, ws + O_H1, NN1, ws + O_DEG);
  bn_stats_kernel<<<512, 256, 0, stream>>>(ws + O_H1, ws + O_BN);
  bn_finalize_kernel<<<1, 128, 0, stream>>>(ws + O_BN, g0, b0, ws + O_SC, ws + O_SH);

  // ================= layer 1 =================
  gemm4_kernel<<<(NN1 + 63) / 64, 256, 0, stream>>>(
      ws + O_H1, ws + O_SC, ws + O_SH,
      Wk1, ws + O_K1, NN1,
      Wv1, ws + O_V1, NN1,
      Wq1, ws + O_Q1, NN2,
      Ws1, ws + O_H2, NN2);
  gemm128_kernel<<<2, 256, 0, stream>>>(tt, Wek1, ws + O_EK, 65, nullptr);
  gemm128_kernel<<<2, 256, 0, stream>>>(at, Wev1, ws + O_EV, 65, nullptr);

  attn_kernel<<<(NN2 + 3) / 4, 256, 0, stream>>>(
      ws + O_Q1, ws + O_K1, ws + O_V1, ws + O_EK, ws + O_EV,
      RP + B1, VALS, ws + O_H2, ws + O_H2, NN2);

  // ================= layer 2 =================
  gemm4_kernel<<<(NN2 + 63) / 64, 256, 0, stream>>>(
      ws + O_H2, nullptr, nullptr,
      Wk2, ws + O_K2, NN2,
      Wv2, ws + O_V2, NN2,
      Wq2, ws + O_Q2, NN3,
      Ws2, ws + O_S2, NN3);

  attn_kernel<<<(NN3 + 3) / 4, 256, 0, stream>>>(
      ws + O_Q2, ws + O_K2, ws + O_V2, nullptr, nullptr,
      RP + B2, VALS, ws + O_S2, (float*)d_out, NN3);

  (void)in_sizes; (void)n_in; (void)out_size; (void)ws_size;
}